// Round 3
// baseline (323.977 us; speedup 1.0000x reference)
//
#include <hip/hip_runtime.h>
#include <math.h>

// Problem constants
#define T_NODES 2048
#define M_WORDS 32
#define D 768
#define DTRAJ 256
#define NCHUNK 16  // t-chunks for word accumulation partials

typedef __attribute__((ext_vector_type(8))) short bhalf8;  // 8 bf16 = 4 VGPRs
typedef __attribute__((ext_vector_type(4))) float f32x4;

// ---------------- Workspace layout (byte offsets, computed) ----------------
constexpr size_t OFF_A1HI = 0;                                      // 2048x256 bf16
constexpr size_t OFF_A1LO = OFF_A1HI + (size_t)T_NODES * DTRAJ * 2;
constexpr size_t OFF_AHI  = OFF_A1LO + (size_t)T_NODES * DTRAJ * 2;  // 2048x768 bf16
constexpr size_t OFF_ALO  = OFF_AHI + (size_t)T_NODES * D * 2;
constexpr size_t OFF_WT1H = OFF_ALO + (size_t)T_NODES * D * 2;       // 768x256 bf16
constexpr size_t OFF_WT1L = OFF_WT1H + (size_t)D * DTRAJ * 2;
constexpr size_t OFF_WT2H = OFF_WT1L + (size_t)D * DTRAJ * 2;        // 768x768 bf16 x6
constexpr size_t OFF_WT2L = OFF_WT2H + (size_t)D * D * 2;
constexpr size_t OFF_WG0H = OFF_WT2L + (size_t)D * D * 2;
constexpr size_t OFF_WG0L = OFF_WG0H + (size_t)D * D * 2;
constexpr size_t OFF_WG1H = OFF_WG0L + (size_t)D * D * 2;
constexpr size_t OFF_WG1L = OFF_WG1H + (size_t)D * D * 2;
constexpr size_t OFF_BUFB = OFF_WG1L + (size_t)D * D * 2;            // 2048x768 f32
constexpr size_t OFF_ALPH = OFF_BUFB + (size_t)T_NODES * D * 4;      // 2048x32 f32
constexpr size_t OFF_WPRT = OFF_ALPH + (size_t)T_NODES * M_WORDS * 4;  // 16x32x768 f32
constexpr size_t OFF_BPRT = OFF_WPRT + (size_t)NCHUNK * M_WORDS * D * 4;  // 16x32 f32
constexpr size_t OFF_INVZ = OFF_BPRT + (size_t)NCHUNK * M_WORDS * 4;
constexpr size_t OFF_INVW = OFF_INVZ + (size_t)T_NODES * 4;

__device__ __forceinline__ float gelu_exact(float x) {
    return 0.5f * x * (1.0f + erff(x * 0.70710678118654752f));
}
__device__ __forceinline__ unsigned short f2bf(float x) {  // RNE
    unsigned int u = __float_as_uint(x);
    return (unsigned short)((u + 0x7fffu + ((u >> 16) & 1u)) >> 16);
}
__device__ __forceinline__ float bf2f(unsigned short b) {
    return __uint_as_float(((unsigned int)b) << 16);
}

__device__ __forceinline__ float wave_reduce_sum(float v) {
#pragma unroll
    for (int off = 32; off > 0; off >>= 1) v += __shfl_down(v, off);
    return v;  // lane 0
}
__device__ __forceinline__ float block_reduce_sum256(float v, float* sbuf) {
    v = wave_reduce_sum(v);
    const int lane = threadIdx.x & 63, wid = threadIdx.x >> 6;
    if (lane == 0) sbuf[wid] = v;
    __syncthreads();
    float r = sbuf[0] + sbuf[1] + sbuf[2] + sbuf[3];
    __syncthreads();
    return r;
}

// LayerNorm of one 768 row, 256 threads (3 elems/thread)
__device__ __forceinline__ void ln_row(const float* __restrict__ x,
                                       const float* __restrict__ g,
                                       const float* __restrict__ b, float* sbuf,
                                       float& y0, float& y1, float& y2) {
    const int tid = threadIdx.x;
    const float x0 = x[tid], x1 = x[tid + 256], x2 = x[tid + 512];
    const float s = block_reduce_sum256(x0 + x1 + x2, sbuf);
    const float mu = s * (1.0f / 768.0f);
    const float d0 = x0 - mu, d1 = x1 - mu, d2 = x2 - mu;
    const float v = block_reduce_sum256(d0 * d0 + d1 * d1 + d2 * d2, sbuf);
    const float rs = rsqrtf(v * (1.0f / 768.0f) + 1e-5f);
    y0 = d0 * rs * g[tid] + b[tid];
    y1 = d1 * rs * g[tid + 256] + b[tid + 256];
    y2 = d2 * rs * g[tid + 512] + b[tid + 512];
}

// ---------------- Conversion kernels ----------------
__global__ __launch_bounds__(256) void cvt_split(const float* __restrict__ x,
                                                 unsigned short* __restrict__ hi,
                                                 unsigned short* __restrict__ lo, int n) {
    const int i = (blockIdx.x * 256 + threadIdx.x) * 4;
    if (i >= n) return;
    const float4 v = *(const float4*)(x + i);
    ushort4 h, l;
    h.x = f2bf(v.x); l.x = f2bf(v.x - bf2f(h.x));
    h.y = f2bf(v.y); l.y = f2bf(v.y - bf2f(h.y));
    h.z = f2bf(v.z); l.z = f2bf(v.z - bf2f(h.z));
    h.w = f2bf(v.w); l.w = f2bf(v.w - bf2f(h.w));
    *(ushort4*)(hi + i) = h;
    *(ushort4*)(lo + i) = l;
}

// W (K x N) fp32 -> Wt (N x K) bf16 hi/lo via 32x32 LDS tile
__device__ __forceinline__ void tr_split_tile(const float* __restrict__ W,
                                              unsigned short* __restrict__ hi,
                                              unsigned short* __restrict__ lo, int K, int N) {
    __shared__ float tile[32][33];
    const int n0 = blockIdx.x * 32, k0 = blockIdx.y * 32;
    const int tx = threadIdx.x & 31, ty = threadIdx.x >> 5;  // ty 0..7
#pragma unroll
    for (int i = 0; i < 32; i += 8)
        tile[ty + i][tx] = W[(size_t)(k0 + ty + i) * N + n0 + tx];
    __syncthreads();
#pragma unroll
    for (int i = 0; i < 32; i += 8) {
        const float v = tile[tx][ty + i];
        const unsigned short h = f2bf(v);
        const size_t o = (size_t)(n0 + ty + i) * K + k0 + tx;
        hi[o] = h;
        lo[o] = f2bf(v - bf2f(h));
    }
}

__global__ __launch_bounds__(256) void cvt_tr_one(const float* __restrict__ W,
                                                  unsigned short* __restrict__ hi,
                                                  unsigned short* __restrict__ lo,
                                                  int K, int N) {
    tr_split_tile(W, hi, lo, K, N);
}

// three 768x768 weights in one launch (blockIdx.z selects)
__global__ __launch_bounds__(256) void cvt_tr3(const float* __restrict__ Wa,
                                               const float* __restrict__ Wb,
                                               const float* __restrict__ Wc,
                                               unsigned short* __restrict__ ha,
                                               unsigned short* __restrict__ la,
                                               unsigned short* __restrict__ hb,
                                               unsigned short* __restrict__ lb,
                                               unsigned short* __restrict__ hc,
                                               unsigned short* __restrict__ lc) {
    const float* W = (blockIdx.z == 0) ? Wa : (blockIdx.z == 1) ? Wb : Wc;
    unsigned short* hi = (blockIdx.z == 0) ? ha : (blockIdx.z == 1) ? hb : hc;
    unsigned short* lo = (blockIdx.z == 0) ? la : (blockIdx.z == 1) ? lb : lc;
    tr_split_tile(W, hi, lo, D, D);
}

// ---------------- MFMA split-bf16 GEMM ----------------
// C[2048 x N_] = act(A @ B + bias). A hi/lo row-major (lda=K_); B TRANSPOSED
// hi/lo (N_ x K_). Block tile 64x128, BK=64, 128 threads = 2 waves, each wave
// 64x64 via 4x4 mfma_f32_16x16x32_bf16 frags. Split product: 3 terms
// (hi*hi + hi*lo + lo*hi), rel err ~2^-17.
// EPI: 0 = fp32 out to C; 1 = gelu then split bf16 out to Ohi/Olo.
#define MFMA_BF16(a, b, c) __builtin_amdgcn_mfma_f32_16x16x32_bf16(a, b, c, 0, 0, 0)

template <int EPI>
__global__ __launch_bounds__(128) void mfma_gemm(
    const unsigned short* __restrict__ Ahi, const unsigned short* __restrict__ Alo,
    const unsigned short* __restrict__ Bthi, const unsigned short* __restrict__ Btlo,
    const float* __restrict__ bias, float* __restrict__ C,
    unsigned short* __restrict__ Ohi, unsigned short* __restrict__ Olo, int N_, int K_) {
    // rows padded to 72 shorts (144 B): frag reads land on 8 disjoint 4-bank
    // classes x 8 lanes -> minimum 8 bank-cycles per wave read (conflict-free).
    __shared__ __align__(16) short sA[2][64 * 72];   // [hi/lo]
    __shared__ __align__(16) short sB[2][128 * 72];

    const int tid = threadIdx.x;
    const int bm = blockIdx.x * 64;
    const int bn = blockIdx.y * 128;
    const int srow = tid >> 3;   // 0..15
    const int sslot = tid & 7;   // 16B slot within a 64-elem k-row
    const int wv = tid >> 6;     // 0..1
    const int lane = tid & 63;
    const int g = lane >> 4, r = lane & 15;
    const int wn = wv * 64;

    f32x4 acc[4][4];
#pragma unroll
    for (int i = 0; i < 4; ++i)
#pragma unroll
        for (int j = 0; j < 4; ++j) acc[i][j] = (f32x4){0.f, 0.f, 0.f, 0.f};

    for (int k0 = 0; k0 < K_; k0 += 64) {
        __syncthreads();  // previous reads done before overwrite
        // stage A (64 rows x 64 k, hi+lo): 4 rows/thread each buffer
#pragma unroll
        for (int i = 0; i < 4; ++i) {
            const int row = srow + i * 16;
            const size_t go = (size_t)(bm + row) * K_ + k0 + sslot * 8;
            *(float4*)(void*)&sA[0][row * 72 + sslot * 8] = *(const float4*)(Ahi + go);
            *(float4*)(void*)&sA[1][row * 72 + sslot * 8] = *(const float4*)(Alo + go);
        }
        // stage B (128 Bt-rows x 64 k, hi+lo): 8 rows/thread each buffer
#pragma unroll
        for (int i = 0; i < 8; ++i) {
            const int row = srow + i * 16;
            const size_t go = (size_t)(bn + row) * K_ + k0 + sslot * 8;
            *(float4*)(void*)&sB[0][row * 72 + sslot * 8] = *(const float4*)(Bthi + go);
            *(float4*)(void*)&sB[1][row * 72 + sslot * 8] = *(const float4*)(Btlo + go);
        }
        __syncthreads();
#pragma unroll
        for (int ks = 0; ks < 2; ++ks) {
            const int kb = ks * 32 + g * 8;  // k-map: k = 8*(lane>>4)+j, same A & B
            bhalf8 a[4][2], b[4][2];
#pragma unroll
            for (int fm = 0; fm < 4; ++fm) {
                a[fm][0] = *(const bhalf8*)(void*)&sA[0][(fm * 16 + r) * 72 + kb];
                a[fm][1] = *(const bhalf8*)(void*)&sA[1][(fm * 16 + r) * 72 + kb];
            }
#pragma unroll
            for (int fn = 0; fn < 4; ++fn) {
                b[fn][0] = *(const bhalf8*)(void*)&sB[0][(wn + fn * 16 + r) * 72 + kb];
                b[fn][1] = *(const bhalf8*)(void*)&sB[1][(wn + fn * 16 + r) * 72 + kb];
            }
#pragma unroll
            for (int fm = 0; fm < 4; ++fm)
#pragma unroll
                for (int fn = 0; fn < 4; ++fn) {
                    acc[fm][fn] = MFMA_BF16(a[fm][0], b[fn][0], acc[fm][fn]);
                    acc[fm][fn] = MFMA_BF16(a[fm][0], b[fn][1], acc[fm][fn]);
                    acc[fm][fn] = MFMA_BF16(a[fm][1], b[fn][0], acc[fm][fn]);
                }
        }
    }

    // C/D layout (HW-verified m89/m91): col = lane&15, row = 4*(lane>>4)+reg
#pragma unroll
    for (int fm = 0; fm < 4; ++fm)
#pragma unroll
        for (int fn = 0; fn < 4; ++fn) {
            const int col = bn + wn + fn * 16 + r;
            const float bv = bias[col];
#pragma unroll
            for (int j = 0; j < 4; ++j) {
                const int row = bm + fm * 16 + g * 4 + j;
                float v = acc[fm][fn][j] + bv;
                if (EPI == 0) {
                    C[(size_t)row * N_ + col] = v;
                } else {
                    v = gelu_exact(v);
                    const unsigned short h = f2bf(v);
                    Ohi[(size_t)row * N_ + col] = h;
                    Olo[(size_t)row * N_ + col] = f2bf(v - bf2f(h));
                }
            }
        }
}

// ---------------- Pointwise / graph kernels ----------------
// blocks [0,2048): h[t] = LN(z[t])*clip(ts), invz; blocks [2048,2080): copy
// word row + invw.
__global__ __launch_bounds__(256) void init_kernel(const float* __restrict__ z,
                                                   const float* __restrict__ g,
                                                   const float* __restrict__ b,
                                                   const float* __restrict__ tsp,
                                                   const float* __restrict__ words,
                                                   float* __restrict__ h,
                                                   float* __restrict__ invz,
                                                   float* __restrict__ invw) {
    __shared__ float sbuf[4];
    const int blk = blockIdx.x;
    if (blk < T_NODES) {
        float y0, y1, y2;
        ln_row(z + (size_t)blk * D, g, b, sbuf, y0, y1, y2);
        const float sc = fminf(fmaxf(tsp[0], 0.05f), 2.0f);
        y0 *= sc; y1 *= sc; y2 *= sc;
        const size_t o = (size_t)blk * D + threadIdx.x;
        h[o] = y0; h[o + 256] = y1; h[o + 512] = y2;
        const float ss = block_reduce_sum256(y0 * y0 + y1 * y1 + y2 * y2, sbuf);
        if (threadIdx.x == 0) invz[blk] = 1.0f / fmaxf(sqrtf(ss), 1e-12f);
    } else {
        const int w = blk - T_NODES;
        const size_t src = (size_t)w * D + threadIdx.x;
        const float x0 = words[src], x1 = words[src + 256], x2 = words[src + 512];
        const size_t dst = (size_t)(T_NODES + w) * D + threadIdx.x;
        h[dst] = x0; h[dst + 256] = x1; h[dst + 512] = x2;
        const float ss = block_reduce_sum256(x0 * x0 + x1 * x1 + x2 * x2, sbuf);
        if (threadIdx.x == 0) invw[w] = 1.0f / fmaxf(sqrtf(ss), 1e-12f);
    }
}

// LN of h rows -> split bf16 hi/lo (GEMM A operand)
__global__ __launch_bounds__(256) void ln_split_kernel(const float* __restrict__ x,
                                                       const float* __restrict__ g,
                                                       const float* __restrict__ b,
                                                       unsigned short* __restrict__ hi,
                                                       unsigned short* __restrict__ lo) {
    __shared__ float sbuf[4];
    const int t = blockIdx.x;
    float y0, y1, y2;
    ln_row(x + (size_t)t * D, g, b, sbuf, y0, y1, y2);
    const size_t o = (size_t)t * D + threadIdx.x;
    unsigned short h;
    h = f2bf(y0); hi[o] = h;       lo[o] = f2bf(y0 - bf2f(h));
    h = f2bf(y1); hi[o + 256] = h; lo[o + 256] = f2bf(y1 - bf2f(h));
    h = f2bf(y2); hi[o + 512] = h; lo[o + 512] = f2bf(y2 - bf2f(h));
}

// row-softmax of normalized z0 . words^T (no beta here; beta from partials)
__global__ __launch_bounds__(256) void softmax_kernel(const float* __restrict__ h,
                                                      const float* __restrict__ wt,
                                                      const float* __restrict__ invz,
                                                      const float* __restrict__ invw,
                                                      const int* __restrict__ vlp,
                                                      float* __restrict__ alpha) {
    const int t = blockIdx.x;
    if (t >= *vlp) return;
    __shared__ float row[D];
    __shared__ float logits[M_WORDS];
    const int tid = threadIdx.x;
    row[tid] = h[(size_t)t * D + tid];
    row[tid + 256] = h[(size_t)t * D + tid + 256];
    row[tid + 512] = h[(size_t)t * D + tid + 512];
    __syncthreads();
    const int wid = tid >> 6, lane = tid & 63;
    const float iz = invz[t];
#pragma unroll
    for (int i = 0; i < 8; ++i) {
        const int w = wid * 8 + i;
        const float* wr = wt + (size_t)w * D;
        float dot = 0.0f;
        for (int e = lane; e < D; e += 64) dot = fmaf(row[e], wr[e], dot);
        dot = wave_reduce_sum(dot);
        if (lane == 0) logits[w] = dot * iz * invw[w];  // TAU = 1
    }
    __syncthreads();
    if (tid < 64) {
        const float val = (tid < 32) ? logits[tid] : -INFINITY;
        float mx = val;
#pragma unroll
        for (int off = 32; off > 0; off >>= 1) mx = fmaxf(mx, __shfl_xor(mx, off));
        const float e = (tid < 32) ? expf(val - mx) : 0.0f;
        float sum = e;
#pragma unroll
        for (int off = 32; off > 0; off >>= 1) sum += __shfl_xor(sum, off);
        if (tid < 32) alpha[(size_t)t * M_WORDS + tid] = e / sum;
    }
}

// blocks [0,1024): grid-stride h[t] += gelu(m[t-1]), 1<=t<VL.
// blocks [1024,1024+NCHUNK*3): wpart[chunk][w][c] = sum_{t in chunk} alpha[t][w]*m[t][c]
//   (c-block of 256); c-block 0 also writes bpart[chunk][w] = sum alpha[t][w].
__global__ __launch_bounds__(256) void gcn_agg_kernel(const float* __restrict__ m,
                                                      const float* __restrict__ alpha,
                                                      const int* __restrict__ vlp,
                                                      float* __restrict__ h,
                                                      float* __restrict__ wpart,
                                                      float* __restrict__ bpart) {
    const int VL = *vlp;
    if (blockIdx.x < 1024) {
        const int total = (T_NODES - 1) * D;
        for (int i = blockIdx.x * 256 + threadIdx.x; i < total; i += 1024 * 256) {
            const int t = 1 + i / D;
            if (t < VL) {
                const int c = i - (t - 1) * D;
                const size_t o = (size_t)t * D + c;
                h[o] += gelu_exact(m[o - D]);
            }
        }
    } else {
        const int bb = blockIdx.x - 1024;
        const int chunk = bb / 3, cb = bb - chunk * 3;
        const int c = cb * 256 + threadIdx.x;
        const int tpc = (VL + NCHUNK - 1) / NCHUNK;
        const int t0 = chunk * tpc;
        const int t1 = min(t0 + tpc, VL);
        float acc[M_WORDS] = {};
        for (int t = t0; t < t1; ++t) {
            const float mv = m[(size_t)t * D + c];
            const float4* a4 = (const float4*)(alpha + (size_t)t * M_WORDS);
#pragma unroll
            for (int q = 0; q < 8; ++q) {
                const float4 a = a4[q];
                acc[q * 4 + 0] = fmaf(a.x, mv, acc[q * 4 + 0]);
                acc[q * 4 + 1] = fmaf(a.y, mv, acc[q * 4 + 1]);
                acc[q * 4 + 2] = fmaf(a.z, mv, acc[q * 4 + 2]);
                acc[q * 4 + 3] = fmaf(a.w, mv, acc[q * 4 + 3]);
            }
        }
#pragma unroll
        for (int w = 0; w < M_WORDS; ++w)
            wpart[((size_t)chunk * M_WORDS + w) * D + c] = acc[w];
        if (cb == 0 && threadIdx.x < M_WORDS) {
            float bs = 0.0f;
            for (int t = t0; t < t1; ++t) bs += alpha[(size_t)t * M_WORDS + threadIdx.x];
            bpart[chunk * M_WORDS + threadIdx.x] = bs;
        }
    }
}

// h[T+w] += gelu( (sum_chunks wpart) * clip(1/(beta+1e-6),.2,5)/max(beta,1) )
__global__ __launch_bounds__(256) void word_fin_kernel(const float* __restrict__ wpart,
                                                       const float* __restrict__ bpart,
                                                       float* __restrict__ h) {
    const int idx = blockIdx.x * 256 + threadIdx.x;
    const int w = idx / D, c = idx - w * D;
    float beta = 0.0f, acc = 0.0f;
#pragma unroll
    for (int q = 0; q < NCHUNK; ++q) {
        beta += bpart[q * M_WORDS + w];
        acc += wpart[((size_t)q * M_WORDS + w) * D + c];
    }
    const float ib = fminf(fmaxf(1.0f / (beta + 1e-6f), 0.2f), 5.0f);
    const float v = acc / fmaxf(beta, 1.0f) * ib;
    h[(size_t)(T_NODES + w) * D + c] += gelu_exact(v);
}

extern "C" void kernel_launch(void* const* d_in, const int* in_sizes, int n_in,
                              void* d_out, int out_size, void* d_ws, size_t ws_size,
                              hipStream_t stream) {
    const float* traj = (const float*)d_in[0];
    const float* words = (const float*)d_in[1];
    // d_in[2], d_in[3]: edge indices — deterministic structure, unused.
    const int* vlp = (const int*)d_in[4];
    const float* W1 = (const float*)d_in[5];
    const float* b1 = (const float*)d_in[6];
    const float* W2 = (const float*)d_in[7];
    const float* b2 = (const float*)d_in[8];
    const float* ln_g = (const float*)d_in[9];
    const float* ln_b = (const float*)d_in[10];
    const float* tsc = (const float*)d_in[11];
    const float* g_ln_g[2] = {(const float*)d_in[12], (const float*)d_in[16]};
    const float* g_ln_b[2] = {(const float*)d_in[13], (const float*)d_in[17]};
    const float* g_W[2] = {(const float*)d_in[14], (const float*)d_in[18]};
    const float* g_b[2] = {(const float*)d_in[15], (const float*)d_in[19]};

    char* wsb = (char*)d_ws;
    unsigned short* A1hi = (unsigned short*)(wsb + OFF_A1HI);
    unsigned short* A1lo = (unsigned short*)(wsb + OFF_A1LO);
    unsigned short* Ahi = (unsigned short*)(wsb + OFF_AHI);
    unsigned short* Alo = (unsigned short*)(wsb + OFF_ALO);
    unsigned short* WT1h = (unsigned short*)(wsb + OFF_WT1H);
    unsigned short* WT1l = (unsigned short*)(wsb + OFF_WT1L);
    unsigned short* WT2h = (unsigned short*)(wsb + OFF_WT2H);
    unsigned short* WT2l = (unsigned short*)(wsb + OFF_WT2L);
    unsigned short* WG0h = (unsigned short*)(wsb + OFF_WG0H);
    unsigned short* WG0l = (unsigned short*)(wsb + OFF_WG0L);
    unsigned short* WG1h = (unsigned short*)(wsb + OFF_WG1H);
    unsigned short* WG1l = (unsigned short*)(wsb + OFF_WG1L);
    float* bufB = (float*)(wsb + OFF_BUFB);
    float* alpha = (float*)(wsb + OFF_ALPH);
    float* wpart = (float*)(wsb + OFF_WPRT);
    float* bpart = (float*)(wsb + OFF_BPRT);
    float* invz = (float*)(wsb + OFF_INVZ);
    float* invw = (float*)(wsb + OFF_INVW);
    float* h = (float*)d_out;

    const unsigned short* WGh[2] = {WG0h, WG1h};
    const unsigned short* WGl[2] = {WG0l, WG1l};

    const dim3 ggrid(T_NODES / 64, D / 128);  // (32, 6)

    // conversions (inputs only; all up front)
    cvt_split<<<(T_NODES * DTRAJ) / 1024, 256, 0, stream>>>(traj, A1hi, A1lo,
                                                            T_NODES * DTRAJ);
    cvt_tr_one<<<dim3(D / 32, DTRAJ / 32), 256, 0, stream>>>(W1, WT1h, WT1l, DTRAJ, D);
    cvt_tr3<<<dim3(D / 32, D / 32, 3), 256, 0, stream>>>(W2, g_W[0], g_W[1], WT2h, WT2l,
                                                         WG0h, WG0l, WG1h, WG1l);

    // MLP: z = gelu(traj @ W1 + b1) @ W2 + b2
    mfma_gemm<1><<<ggrid, 128, 0, stream>>>(A1hi, A1lo, WT1h, WT1l, b1, nullptr, Ahi, Alo,
                                            D, DTRAJ);
    mfma_gemm<0><<<ggrid, 128, 0, stream>>>(Ahi, Alo, WT2h, WT2l, b2, bufB, nullptr,
                                            nullptr, D, D);

    // h init (+ row norms) and alpha
    init_kernel<<<T_NODES + M_WORDS, 256, 0, stream>>>(bufB, ln_g, ln_b, tsc, words, h,
                                                       invz, invw);
    softmax_kernel<<<T_NODES, 256, 0, stream>>>(h, words, invz, invw, vlp, alpha);

    // two GCN layers
    for (int l = 0; l < 2; ++l) {
        ln_split_kernel<<<T_NODES, 256, 0, stream>>>(h, g_ln_g[l], g_ln_b[l], Ahi, Alo);
        mfma_gemm<0><<<ggrid, 128, 0, stream>>>(Ahi, Alo, WGh[l], WGl[l], g_b[l], bufB,
                                                nullptr, nullptr, D, D);
        gcn_agg_kernel<<<1024 + NCHUNK * 3, 256, 0, stream>>>(bufB, alpha, vlp, h, wpart,
                                                              bpart);
        word_fin_kernel<<<(M_WORDS * D) / 256, 256, 0, stream>>>(wpart, bpart, h);
    }
}

// Round 4
// 263.750 us; speedup vs baseline: 1.2283x; 1.2283x over previous
//
#include <hip/hip_runtime.h>
#include <math.h>

// Problem constants
#define T_NODES 2048
#define M_WORDS 32
#define D 768
#define DTRAJ 256
#define NCHUNK 128  // t-chunks for word accumulation partials

typedef __attribute__((ext_vector_type(8))) short bhalf8;  // 8 bf16 = 4 VGPRs
typedef __attribute__((ext_vector_type(4))) float f32x4;

// ---------------- Workspace layout (byte offsets, computed) ----------------
constexpr size_t OFF_A1HI = 0;                                      // 2048x256 bf16
constexpr size_t OFF_A1LO = OFF_A1HI + (size_t)T_NODES * DTRAJ * 2;
constexpr size_t OFF_AHI  = OFF_A1LO + (size_t)T_NODES * DTRAJ * 2;  // 2048x768 bf16
constexpr size_t OFF_ALO  = OFF_AHI + (size_t)T_NODES * D * 2;
constexpr size_t OFF_WT1H = OFF_ALO + (size_t)T_NODES * D * 2;       // 768x256 bf16
constexpr size_t OFF_WT1L = OFF_WT1H + (size_t)D * DTRAJ * 2;
constexpr size_t OFF_WT2H = OFF_WT1L + (size_t)D * DTRAJ * 2;        // 768x768 bf16 x6
constexpr size_t OFF_WT2L = OFF_WT2H + (size_t)D * D * 2;
constexpr size_t OFF_WG0H = OFF_WT2L + (size_t)D * D * 2;
constexpr size_t OFF_WG0L = OFF_WG0H + (size_t)D * D * 2;
constexpr size_t OFF_WG1H = OFF_WG0L + (size_t)D * D * 2;
constexpr size_t OFF_WG1L = OFF_WG1H + (size_t)D * D * 2;
constexpr size_t OFF_BUFB = OFF_WG1L + (size_t)D * D * 2;            // 2048x768 f32
constexpr size_t OFF_ALPH = OFF_BUFB + (size_t)T_NODES * D * 4;      // 2048x32 f32
constexpr size_t OFF_WPRT = OFF_ALPH + (size_t)T_NODES * M_WORDS * 4;  // 128x32x768 f32
constexpr size_t OFF_BPRT = OFF_WPRT + (size_t)NCHUNK * M_WORDS * D * 4;  // 128x32 f32
constexpr size_t OFF_INVZ = OFF_BPRT + (size_t)NCHUNK * M_WORDS * 4;
constexpr size_t OFF_INVW = OFF_INVZ + (size_t)T_NODES * 4;

__device__ __forceinline__ float gelu_exact(float x) {
    return 0.5f * x * (1.0f + erff(x * 0.70710678118654752f));
}
__device__ __forceinline__ unsigned short f2bf(float x) {  // RNE
    unsigned int u = __float_as_uint(x);
    return (unsigned short)((u + 0x7fffu + ((u >> 16) & 1u)) >> 16);
}
__device__ __forceinline__ float bf2f(unsigned short b) {
    return __uint_as_float(((unsigned int)b) << 16);
}

__device__ __forceinline__ float wave_reduce_sum(float v) {
#pragma unroll
    for (int off = 32; off > 0; off >>= 1) v += __shfl_down(v, off);
    return v;  // lane 0
}
__device__ __forceinline__ float block_reduce_sum256(float v, float* sbuf) {
    v = wave_reduce_sum(v);
    const int lane = threadIdx.x & 63, wid = threadIdx.x >> 6;
    if (lane == 0) sbuf[wid] = v;
    __syncthreads();
    float r = sbuf[0] + sbuf[1] + sbuf[2] + sbuf[3];
    __syncthreads();
    return r;
}

// LayerNorm of one 768 row, 256 threads (3 elems/thread)
__device__ __forceinline__ void ln_row(const float* __restrict__ x,
                                       const float* __restrict__ g,
                                       const float* __restrict__ b, float* sbuf,
                                       float& y0, float& y1, float& y2) {
    const int tid = threadIdx.x;
    const float x0 = x[tid], x1 = x[tid + 256], x2 = x[tid + 512];
    const float s = block_reduce_sum256(x0 + x1 + x2, sbuf);
    const float mu = s * (1.0f / 768.0f);
    const float d0 = x0 - mu, d1 = x1 - mu, d2 = x2 - mu;
    const float v = block_reduce_sum256(d0 * d0 + d1 * d1 + d2 * d2, sbuf);
    const float rs = rsqrtf(v * (1.0f / 768.0f) + 1e-5f);
    y0 = d0 * rs * g[tid] + b[tid];
    y1 = d1 * rs * g[tid + 256] + b[tid + 256];
    y2 = d2 * rs * g[tid + 512] + b[tid + 512];
}

// ---------------- Conversion kernels ----------------
__global__ __launch_bounds__(256) void cvt_split(const float* __restrict__ x,
                                                 unsigned short* __restrict__ hi,
                                                 unsigned short* __restrict__ lo, int n) {
    const int i = (blockIdx.x * 256 + threadIdx.x) * 4;
    if (i >= n) return;
    const float4 v = *(const float4*)(x + i);
    ushort4 h, l;
    h.x = f2bf(v.x); l.x = f2bf(v.x - bf2f(h.x));
    h.y = f2bf(v.y); l.y = f2bf(v.y - bf2f(h.y));
    h.z = f2bf(v.z); l.z = f2bf(v.z - bf2f(h.z));
    h.w = f2bf(v.w); l.w = f2bf(v.w - bf2f(h.w));
    *(ushort4*)(hi + i) = h;
    *(ushort4*)(lo + i) = l;
}

// W (K x N) fp32 -> Wt (N x K) bf16 hi/lo via 32x32 LDS tile
__device__ __forceinline__ void tr_split_tile(const float* __restrict__ W,
                                              unsigned short* __restrict__ hi,
                                              unsigned short* __restrict__ lo, int K, int N) {
    __shared__ float tile[32][33];
    const int n0 = blockIdx.x * 32, k0 = blockIdx.y * 32;
    const int tx = threadIdx.x & 31, ty = threadIdx.x >> 5;  // ty 0..7
#pragma unroll
    for (int i = 0; i < 32; i += 8)
        tile[ty + i][tx] = W[(size_t)(k0 + ty + i) * N + n0 + tx];
    __syncthreads();
#pragma unroll
    for (int i = 0; i < 32; i += 8) {
        const float v = tile[tx][ty + i];
        const unsigned short h = f2bf(v);
        const size_t o = (size_t)(n0 + ty + i) * K + k0 + tx;
        hi[o] = h;
        lo[o] = f2bf(v - bf2f(h));
    }
}

__global__ __launch_bounds__(256) void cvt_tr_one(const float* __restrict__ W,
                                                  unsigned short* __restrict__ hi,
                                                  unsigned short* __restrict__ lo,
                                                  int K, int N) {
    tr_split_tile(W, hi, lo, K, N);
}

// three 768x768 weights in one launch (blockIdx.z selects)
__global__ __launch_bounds__(256) void cvt_tr3(const float* __restrict__ Wa,
                                               const float* __restrict__ Wb,
                                               const float* __restrict__ Wc,
                                               unsigned short* __restrict__ ha,
                                               unsigned short* __restrict__ la,
                                               unsigned short* __restrict__ hb,
                                               unsigned short* __restrict__ lb,
                                               unsigned short* __restrict__ hc,
                                               unsigned short* __restrict__ lc) {
    const float* W = (blockIdx.z == 0) ? Wa : (blockIdx.z == 1) ? Wb : Wc;
    unsigned short* hi = (blockIdx.z == 0) ? ha : (blockIdx.z == 1) ? hb : hc;
    unsigned short* lo = (blockIdx.z == 0) ? la : (blockIdx.z == 1) ? lb : lc;
    tr_split_tile(W, hi, lo, D, D);
}

// ---------------- MFMA split-bf16 GEMM (v2: dbuf, high occupancy) ----------------
// C[2048 x N_] = act(A @ B + bias). A hi/lo row-major (lda=K_); B TRANSPOSED
// hi/lo (N_ x K_). Block tile 64x64, BK=32 double-buffered, 128 threads =
// 2 waves, each wave 32x64 via 2x4 mfma_f32_16x16x32_bf16 frags. Split-3
// product (hi*hi + hi*lo + lo*hi). LDS 40 KB -> 3 blocks/CU, 6 waves/CU.
// EPI: 0 = fp32 out to C; 1 = gelu then split bf16 out to Ohi/Olo.
#define MFMA_BF16(a, b, c) __builtin_amdgcn_mfma_f32_16x16x32_bf16(a, b, c, 0, 0, 0)

template <int EPI>
__global__ __launch_bounds__(128, 2) void mfma_gemm(
    const unsigned short* __restrict__ Ahi, const unsigned short* __restrict__ Alo,
    const unsigned short* __restrict__ Bthi, const unsigned short* __restrict__ Btlo,
    const float* __restrict__ bias, float* __restrict__ C,
    unsigned short* __restrict__ Ohi, unsigned short* __restrict__ Olo, int N_, int K_) {
    // rows padded to 40 shorts (80 B): 16-lane frag reads hit 8 disjoint
    // 4-bank groups x 2 lanes -> free 2-way aliasing (m136).
    __shared__ __align__(16) short sA[2][2][64 * 40];  // [buf][hi/lo]
    __shared__ __align__(16) short sB[2][2][64 * 40];

    const int tid = threadIdx.x;
    const int bm = blockIdx.x * 64;
    const int bn = blockIdx.y * 64;
    const int srow = tid >> 2;   // 0..31 (staging: rows srow and srow+32)
    const int sslot = tid & 3;   // 8-short slot within 32-k row
    const int wv = tid >> 6;     // 0..1
    const int lane = tid & 63;
    const int g = lane >> 4, r = lane & 15;
    const int wm = wv * 32;
    const int kb = g * 8;        // k-map: k = 8*(lane>>4)+j, same for A & B

    f32x4 acc[2][4];
#pragma unroll
    for (int i = 0; i < 2; ++i)
#pragma unroll
        for (int j = 0; j < 4; ++j) acc[i][j] = (f32x4){0.f, 0.f, 0.f, 0.f};

    const int NT = K_ >> 5;

    // prologue: stage k-tile 0 into buf 0
    {
        const size_t gA0 = (size_t)(bm + srow) * K_ + sslot * 8;
        const size_t gA1 = (size_t)(bm + srow + 32) * K_ + sslot * 8;
        const size_t gB0 = (size_t)(bn + srow) * K_ + sslot * 8;
        const size_t gB1 = (size_t)(bn + srow + 32) * K_ + sslot * 8;
        const int l0 = srow * 40 + sslot * 8, l1 = (srow + 32) * 40 + sslot * 8;
        *(float4*)(void*)&sA[0][0][l0] = *(const float4*)(Ahi + gA0);
        *(float4*)(void*)&sA[0][0][l1] = *(const float4*)(Ahi + gA1);
        *(float4*)(void*)&sA[0][1][l0] = *(const float4*)(Alo + gA0);
        *(float4*)(void*)&sA[0][1][l1] = *(const float4*)(Alo + gA1);
        *(float4*)(void*)&sB[0][0][l0] = *(const float4*)(Bthi + gB0);
        *(float4*)(void*)&sB[0][0][l1] = *(const float4*)(Bthi + gB1);
        *(float4*)(void*)&sB[0][1][l0] = *(const float4*)(Btlo + gB0);
        *(float4*)(void*)&sB[0][1][l1] = *(const float4*)(Btlo + gB1);
    }
    __syncthreads();

    for (int kt = 0; kt < NT; ++kt) {
        const int cur = kt & 1, nxt = cur ^ 1;
        const bool pf = (kt + 1 < NT);
        float4 pA0, pA1, pL0, pL1, pB0, pB1, pM0, pM1;
        if (pf) {  // issue next-tile global loads early; latency hides under MFMA
            const int k0 = (kt + 1) << 5;
            const size_t gA0 = (size_t)(bm + srow) * K_ + k0 + sslot * 8;
            const size_t gA1 = (size_t)(bm + srow + 32) * K_ + k0 + sslot * 8;
            const size_t gB0 = (size_t)(bn + srow) * K_ + k0 + sslot * 8;
            const size_t gB1 = (size_t)(bn + srow + 32) * K_ + k0 + sslot * 8;
            pA0 = *(const float4*)(Ahi + gA0);
            pA1 = *(const float4*)(Ahi + gA1);
            pL0 = *(const float4*)(Alo + gA0);
            pL1 = *(const float4*)(Alo + gA1);
            pB0 = *(const float4*)(Bthi + gB0);
            pB1 = *(const float4*)(Bthi + gB1);
            pM0 = *(const float4*)(Btlo + gB0);
            pM1 = *(const float4*)(Btlo + gB1);
        }
        // compute current tile
        bhalf8 af[2][2], bf[4][2];
#pragma unroll
        for (int fm = 0; fm < 2; ++fm) {
            af[fm][0] = *(const bhalf8*)(void*)&sA[cur][0][(wm + fm * 16 + r) * 40 + kb];
            af[fm][1] = *(const bhalf8*)(void*)&sA[cur][1][(wm + fm * 16 + r) * 40 + kb];
        }
#pragma unroll
        for (int fn = 0; fn < 4; ++fn) {
            bf[fn][0] = *(const bhalf8*)(void*)&sB[cur][0][(fn * 16 + r) * 40 + kb];
            bf[fn][1] = *(const bhalf8*)(void*)&sB[cur][1][(fn * 16 + r) * 40 + kb];
        }
#pragma unroll
        for (int fm = 0; fm < 2; ++fm)
#pragma unroll
            for (int fn = 0; fn < 4; ++fn) {
                acc[fm][fn] = MFMA_BF16(af[fm][0], bf[fn][0], acc[fm][fn]);
                acc[fm][fn] = MFMA_BF16(af[fm][0], bf[fn][1], acc[fm][fn]);
                acc[fm][fn] = MFMA_BF16(af[fm][1], bf[fn][0], acc[fm][fn]);
            }
        if (pf) {  // write prefetched tile to the other buffer
            const int l0 = srow * 40 + sslot * 8, l1 = (srow + 32) * 40 + sslot * 8;
            *(float4*)(void*)&sA[nxt][0][l0] = pA0;
            *(float4*)(void*)&sA[nxt][0][l1] = pA1;
            *(float4*)(void*)&sA[nxt][1][l0] = pL0;
            *(float4*)(void*)&sA[nxt][1][l1] = pL1;
            *(float4*)(void*)&sB[nxt][0][l0] = pB0;
            *(float4*)(void*)&sB[nxt][0][l1] = pB1;
            *(float4*)(void*)&sB[nxt][1][l0] = pM0;
            *(float4*)(void*)&sB[nxt][1][l1] = pM1;
        }
        __syncthreads();  // one barrier per k-tile
    }

    // C/D layout (HW-verified m89/m91): col = lane&15, row = 4*(lane>>4)+reg
#pragma unroll
    for (int fm = 0; fm < 2; ++fm)
#pragma unroll
        for (int fn = 0; fn < 4; ++fn) {
            const int col = bn + fn * 16 + r;
            const float bv = bias[col];
#pragma unroll
            for (int j = 0; j < 4; ++j) {
                const int row = bm + wm + fm * 16 + g * 4 + j;
                float v = acc[fm][fn][j] + bv;
                if (EPI == 0) {
                    C[(size_t)row * N_ + col] = v;
                } else {
                    v = gelu_exact(v);
                    const unsigned short h = f2bf(v);
                    Ohi[(size_t)row * N_ + col] = h;
                    Olo[(size_t)row * N_ + col] = f2bf(v - bf2f(h));
                }
            }
        }
}

// ---------------- Pointwise / graph kernels ----------------
// blocks [0,2048): h[t] = LN(z[t])*clip(ts), invz; blocks [2048,2080): copy
// word row + invw.
__global__ __launch_bounds__(256) void init_kernel(const float* __restrict__ z,
                                                   const float* __restrict__ g,
                                                   const float* __restrict__ b,
                                                   const float* __restrict__ tsp,
                                                   const float* __restrict__ words,
                                                   float* __restrict__ h,
                                                   float* __restrict__ invz,
                                                   float* __restrict__ invw) {
    __shared__ float sbuf[4];
    const int blk = blockIdx.x;
    if (blk < T_NODES) {
        float y0, y1, y2;
        ln_row(z + (size_t)blk * D, g, b, sbuf, y0, y1, y2);
        const float sc = fminf(fmaxf(tsp[0], 0.05f), 2.0f);
        y0 *= sc; y1 *= sc; y2 *= sc;
        const size_t o = (size_t)blk * D + threadIdx.x;
        h[o] = y0; h[o + 256] = y1; h[o + 512] = y2;
        const float ss = block_reduce_sum256(y0 * y0 + y1 * y1 + y2 * y2, sbuf);
        if (threadIdx.x == 0) invz[blk] = 1.0f / fmaxf(sqrtf(ss), 1e-12f);
    } else {
        const int w = blk - T_NODES;
        const size_t src = (size_t)w * D + threadIdx.x;
        const float x0 = words[src], x1 = words[src + 256], x2 = words[src + 512];
        const size_t dst = (size_t)(T_NODES + w) * D + threadIdx.x;
        h[dst] = x0; h[dst + 256] = x1; h[dst + 512] = x2;
        const float ss = block_reduce_sum256(x0 * x0 + x1 * x1 + x2 * x2, sbuf);
        if (threadIdx.x == 0) invw[w] = 1.0f / fmaxf(sqrtf(ss), 1e-12f);
    }
}

// LN of h rows -> split bf16 hi/lo (GEMM A operand)
__global__ __launch_bounds__(256) void ln_split_kernel(const float* __restrict__ x,
                                                       const float* __restrict__ g,
                                                       const float* __restrict__ b,
                                                       unsigned short* __restrict__ hi,
                                                       unsigned short* __restrict__ lo) {
    __shared__ float sbuf[4];
    const int t = blockIdx.x;
    float y0, y1, y2;
    ln_row(x + (size_t)t * D, g, b, sbuf, y0, y1, y2);
    const size_t o = (size_t)t * D + threadIdx.x;
    unsigned short h;
    h = f2bf(y0); hi[o] = h;       lo[o] = f2bf(y0 - bf2f(h));
    h = f2bf(y1); hi[o + 256] = h; lo[o + 256] = f2bf(y1 - bf2f(h));
    h = f2bf(y2); hi[o + 512] = h; lo[o + 512] = f2bf(y2 - bf2f(h));
}

// row-softmax of normalized z0 . words^T
__global__ __launch_bounds__(256) void softmax_kernel(const float* __restrict__ h,
                                                      const float* __restrict__ wt,
                                                      const float* __restrict__ invz,
                                                      const float* __restrict__ invw,
                                                      const int* __restrict__ vlp,
                                                      float* __restrict__ alpha) {
    const int t = blockIdx.x;
    if (t >= *vlp) return;
    __shared__ float row[D];
    __shared__ float logits[M_WORDS];
    const int tid = threadIdx.x;
    row[tid] = h[(size_t)t * D + tid];
    row[tid + 256] = h[(size_t)t * D + tid + 256];
    row[tid + 512] = h[(size_t)t * D + tid + 512];
    __syncthreads();
    const int wid = tid >> 6, lane = tid & 63;
    const float iz = invz[t];
#pragma unroll
    for (int i = 0; i < 8; ++i) {
        const int w = wid * 8 + i;
        const float* wr = wt + (size_t)w * D;
        float dot = 0.0f;
        for (int e = lane; e < D; e += 64) dot = fmaf(row[e], wr[e], dot);
        dot = wave_reduce_sum(dot);
        if (lane == 0) logits[w] = dot * iz * invw[w];  // TAU = 1
    }
    __syncthreads();
    if (tid < 64) {
        const float val = (tid < 32) ? logits[tid] : -INFINITY;
        float mx = val;
#pragma unroll
        for (int off = 32; off > 0; off >>= 1) mx = fmaxf(mx, __shfl_xor(mx, off));
        const float e = (tid < 32) ? expf(val - mx) : 0.0f;
        float sum = e;
#pragma unroll
        for (int off = 32; off > 0; off >>= 1) sum += __shfl_xor(sum, off);
        if (tid < 32) alpha[(size_t)t * M_WORDS + tid] = e / sum;
    }
}

// Merged per-layer aggregation. Grid (NCHUNK, 3), 256 thr.
// Each block: t-chunk x 256-col slice. For t in chunk:
//   h[t+1][c] += gelu(m[t][c])           (t+1 < VL)   [temporal edge]
//   acc[w]    += alpha[t][w] * m[t][c]                [semantic partial]
// Writes wpart[chunk][w][c]; cb==0 also bpart[chunk][w] = sum alpha.
__global__ __launch_bounds__(256) void gcn_agg_kernel(const float* __restrict__ m,
                                                      const float* __restrict__ alpha,
                                                      const int* __restrict__ vlp,
                                                      float* __restrict__ h,
                                                      float* __restrict__ wpart,
                                                      float* __restrict__ bpart) {
    const int VL = *vlp;
    const int chunk = blockIdx.x, cb = blockIdx.y;
    const int c = cb * 256 + threadIdx.x;
    const int tpc = (VL + NCHUNK - 1) / NCHUNK;
    const int t0 = chunk * tpc;
    const int t1 = min(t0 + tpc, VL);
    float acc[M_WORDS] = {};
    for (int t = t0; t < t1; ++t) {
        const float mv = m[(size_t)t * D + c];
        if (t + 1 < VL) h[(size_t)(t + 1) * D + c] += gelu_exact(mv);
        const float4* a4 = (const float4*)(alpha + (size_t)t * M_WORDS);
#pragma unroll
        for (int q = 0; q < 8; ++q) {
            const float4 a = a4[q];
            acc[q * 4 + 0] = fmaf(a.x, mv, acc[q * 4 + 0]);
            acc[q * 4 + 1] = fmaf(a.y, mv, acc[q * 4 + 1]);
            acc[q * 4 + 2] = fmaf(a.z, mv, acc[q * 4 + 2]);
            acc[q * 4 + 3] = fmaf(a.w, mv, acc[q * 4 + 3]);
        }
    }
#pragma unroll
    for (int w = 0; w < M_WORDS; ++w)
        wpart[((size_t)chunk * M_WORDS + w) * D + c] = acc[w];
    if (cb == 0 && threadIdx.x < M_WORDS) {
        float bs = 0.0f;
        for (int t = t0; t < t1; ++t) bs += alpha[(size_t)t * M_WORDS + threadIdx.x];
        bpart[chunk * M_WORDS + threadIdx.x] = bs;
    }
}

// h[T+w] += gelu( (sum_chunks wpart) * clip(1/(beta+1e-6),.2,5)/max(beta,1) )
__global__ __launch_bounds__(256) void word_fin_kernel(const float* __restrict__ wpart,
                                                       const float* __restrict__ bpart,
                                                       float* __restrict__ h) {
    const int idx = blockIdx.x * 256 + threadIdx.x;
    const int w = idx / D, c = idx - w * D;
    float beta = 0.0f, acc = 0.0f;
#pragma unroll 8
    for (int q = 0; q < NCHUNK; ++q) {
        beta += bpart[q * M_WORDS + w];
        acc += wpart[((size_t)q * M_WORDS + w) * D + c];
    }
    const float ib = fminf(fmaxf(1.0f / (beta + 1e-6f), 0.2f), 5.0f);
    const float v = acc / fmaxf(beta, 1.0f) * ib;
    h[(size_t)(T_NODES + w) * D + c] += gelu_exact(v);
}

extern "C" void kernel_launch(void* const* d_in, const int* in_sizes, int n_in,
                              void* d_out, int out_size, void* d_ws, size_t ws_size,
                              hipStream_t stream) {
    const float* traj = (const float*)d_in[0];
    const float* words = (const float*)d_in[1];
    // d_in[2], d_in[3]: edge indices — deterministic structure, unused.
    const int* vlp = (const int*)d_in[4];
    const float* W1 = (const float*)d_in[5];
    const float* b1 = (const float*)d_in[6];
    const float* W2 = (const float*)d_in[7];
    const float* b2 = (const float*)d_in[8];
    const float* ln_g = (const float*)d_in[9];
    const float* ln_b = (const float*)d_in[10];
    const float* tsc = (const float*)d_in[11];
    const float* g_ln_g[2] = {(const float*)d_in[12], (const float*)d_in[16]};
    const float* g_ln_b[2] = {(const float*)d_in[13], (const float*)d_in[17]};
    const float* g_W[2] = {(const float*)d_in[14], (const float*)d_in[18]};
    const float* g_b[2] = {(const float*)d_in[15], (const float*)d_in[19]};

    char* wsb = (char*)d_ws;
    unsigned short* A1hi = (unsigned short*)(wsb + OFF_A1HI);
    unsigned short* A1lo = (unsigned short*)(wsb + OFF_A1LO);
    unsigned short* Ahi = (unsigned short*)(wsb + OFF_AHI);
    unsigned short* Alo = (unsigned short*)(wsb + OFF_ALO);
    unsigned short* WT1h = (unsigned short*)(wsb + OFF_WT1H);
    unsigned short* WT1l = (unsigned short*)(wsb + OFF_WT1L);
    unsigned short* WT2h = (unsigned short*)(wsb + OFF_WT2H);
    unsigned short* WT2l = (unsigned short*)(wsb + OFF_WT2L);
    unsigned short* WG0h = (unsigned short*)(wsb + OFF_WG0H);
    unsigned short* WG0l = (unsigned short*)(wsb + OFF_WG0L);
    unsigned short* WG1h = (unsigned short*)(wsb + OFF_WG1H);
    unsigned short* WG1l = (unsigned short*)(wsb + OFF_WG1L);
    float* bufB = (float*)(wsb + OFF_BUFB);
    float* alpha = (float*)(wsb + OFF_ALPH);
    float* wpart = (float*)(wsb + OFF_WPRT);
    float* bpart = (float*)(wsb + OFF_BPRT);
    float* invz = (float*)(wsb + OFF_INVZ);
    float* invw = (float*)(wsb + OFF_INVW);
    float* h = (float*)d_out;

    const unsigned short* WGh[2] = {WG0h, WG1h};
    const unsigned short* WGl[2] = {WG0l, WG1l};

    const dim3 ggrid(T_NODES / 64, D / 64);  // (32, 12) = 384 blocks

    // conversions (inputs only; all up front)
    cvt_split<<<(T_NODES * DTRAJ) / 1024, 256, 0, stream>>>(traj, A1hi, A1lo,
                                                            T_NODES * DTRAJ);
    cvt_tr_one<<<dim3(D / 32, DTRAJ / 32), 256, 0, stream>>>(W1, WT1h, WT1l, DTRAJ, D);
    cvt_tr3<<<dim3(D / 32, D / 32, 3), 256, 0, stream>>>(W2, g_W[0], g_W[1], WT2h, WT2l,
                                                         WG0h, WG0l, WG1h, WG1l);

    // MLP: z = gelu(traj @ W1 + b1) @ W2 + b2
    mfma_gemm<1><<<ggrid, 128, 0, stream>>>(A1hi, A1lo, WT1h, WT1l, b1, nullptr, Ahi, Alo,
                                            D, DTRAJ);
    mfma_gemm<0><<<ggrid, 128, 0, stream>>>(Ahi, Alo, WT2h, WT2l, b2, bufB, nullptr,
                                            nullptr, D, D);

    // h init (+ row norms) and alpha
    init_kernel<<<T_NODES + M_WORDS, 256, 0, stream>>>(bufB, ln_g, ln_b, tsc, words, h,
                                                       invz, invw);
    softmax_kernel<<<T_NODES, 256, 0, stream>>>(h, words, invz, invw, vlp, alpha);

    // two GCN layers
    for (int l = 0; l < 2; ++l) {
        ln_split_kernel<<<T_NODES, 256, 0, stream>>>(h, g_ln_g[l], g_ln_b[l], Ahi, Alo);
        mfma_gemm<0><<<ggrid, 128, 0, stream>>>(Ahi, Alo, WGh[l], WGl[l], g_b[l], bufB,
                                                nullptr, nullptr, D, D);
        gcn_agg_kernel<<<dim3(NCHUNK, 3), 256, 0, stream>>>(bufB, alpha, vlp, h, wpart,
                                                            bpart);
        word_fin_kernel<<<(M_WORDS * D) / 256, 256, 0, stream>>>(wpart, bpart, h);
    }
}